// Round 4
// baseline (147.289 us; speedup 1.0000x reference)
//
#include <hip/hip_runtime.h>
#include <hip/hip_bf16.h>

// Grouped masked GEMM (DeepSeekMOE up/gate + down), fp32 in/out, bf16 MFMA.
// G=8, M=32. up/gate: K=4096,N=2816. down: K=1408,N=4096. out: [G,32,5632] f32.
//
// R3: barrier-free wave-sized units. One 64-thread block = one wave = one
// 32m x 32n output tile over full K. W global->reg direct (no LDS), X from
// L2 (XCD-affine: group = blockIdx&7). 2-stage register pipeline, static
// names (rule #20). All 1728 units co-resident from t=0 -> no block tail.

#define G_    8
#define M_    32
#define KUG   4096
#define NUG   2816
#define KDN   1408
#define NDN   4096
#define NOUT  (NUG + NDN)      // 5632
#define UPT   (NUG / 32)       // 88 up units per group
#define DNT   (NDN / 32)       // 128 down units per group
#define UPG   (UPT + DNT)      // 216 units per group

typedef __attribute__((ext_vector_type(8))) short bf16x8;
typedef __attribute__((ext_vector_type(4))) float f32x4;

// fp32 -> bf16 RNE via compiler (m240: don't hand-write cvt_pk asm).
__device__ __forceinline__ short f2bf(float x) {
  union { __hip_bfloat16 h; short s; } u;
  u.h = __hip_bfloat16(x);
  return u.s;
}

__device__ __forceinline__ bf16x8 cvt8(f32x4 lo, f32x4 hi) {
  bf16x8 o;
#pragma unroll
  for (int j = 0; j < 4; ++j) { o[j] = f2bf(lo[j]); o[4 + j] = f2bf(hi[j]); }
  return o;
}

// Load one pipeline stage: W frags (2 x 16 n-rows) + X frags (2 x 16 m-rows),
// 8 contiguous f32 per lane per frag-row -> 8 global_load_dwordx4.
#define LOADST(W, X, k0)                                        \
  do {                                                          \
    W[0][0] = *(const f32x4*)(wp0 + (k0));                      \
    W[0][1] = *(const f32x4*)(wp0 + (k0) + 4);                  \
    W[1][0] = *(const f32x4*)(wp1 + (k0));                      \
    W[1][1] = *(const f32x4*)(wp1 + (k0) + 4);                  \
    X[0][0] = *(const f32x4*)(xp0 + (k0));                      \
    X[0][1] = *(const f32x4*)(xp0 + (k0) + 4);                  \
    X[1][0] = *(const f32x4*)(xp1 + (k0));                      \
    X[1][1] = *(const f32x4*)(xp1 + (k0) + 4);                  \
  } while (0)

// cvt + 4 MFMA: acc[mf][nf] += Xfrag(mf) * Wfrag(nf); C rows = m (X), cols = n (W)
// (operand convention verified in R0: mfma(Xfrag, Wfrag) -> C[m][n]).
#define COMPST(W, X)                                                      \
  do {                                                                    \
    bf16x8 a0 = cvt8(X[0][0], X[0][1]);                                   \
    bf16x8 a1 = cvt8(X[1][0], X[1][1]);                                   \
    bf16x8 b0 = cvt8(W[0][0], W[0][1]);                                   \
    bf16x8 b1 = cvt8(W[1][0], W[1][1]);                                   \
    acc00 = __builtin_amdgcn_mfma_f32_16x16x32_bf16(a0, b0, acc00, 0, 0, 0); \
    acc01 = __builtin_amdgcn_mfma_f32_16x16x32_bf16(a0, b1, acc01, 0, 0, 0); \
    acc10 = __builtin_amdgcn_mfma_f32_16x16x32_bf16(a1, b0, acc10, 0, 0, 0); \
    acc11 = __builtin_amdgcn_mfma_f32_16x16x32_bf16(a1, b1, acc11, 0, 0, 0); \
  } while (0)

__global__ __launch_bounds__(64, 4) void moe_masked_gemm(
    const float* __restrict__ x_ug, const float* __restrict__ w_ug,
    const float* __restrict__ x_dn, const float* __restrict__ w_dn,
    const int* __restrict__ masked_m, float* __restrict__ out) {
  int b = blockIdx.x;
  int g = b & 7;        // group -> XCD affinity (blocks round-robin XCDs by id)
  int u = b >> 3;       // unit within group: [0,UPT) up, [UPT,UPG) down

  const float* wg;
  const float* xg;
  int K, NIT, n0, colOff;
  if (u < UPT) {
    K = KUG; NIT = KUG / 32; n0 = u * 32; colOff = 0;
    wg = w_ug + ((size_t)g * NUG + n0) * KUG;
    xg = x_ug + (size_t)g * M_ * KUG;
  } else {
    int ud = u - UPT;
    K = KDN; NIT = KDN / 32; n0 = ud * 32; colOff = NUG;
    wg = w_dn + ((size_t)g * NDN + n0) * KDN;
    xg = x_dn + (size_t)g * M_ * KDN;
  }

  int mm = masked_m[g];
  int t = threadIdx.x, r = t & 15, q = t >> 4;   // frag row r, k-quad q

  // Per-lane stream bases: frag row = r (rows 0..15) / r+16, 8 f32 at q*8.
  const float* wp0 = wg + (size_t)r * K + q * 8;
  const float* wp1 = wp0 + (size_t)16 * K;
  const float* xp0 = xg + (size_t)r * K + q * 8;
  const float* xp1 = xp0 + (size_t)16 * K;

  f32x4 acc00 = {0.f, 0.f, 0.f, 0.f}, acc01 = {0.f, 0.f, 0.f, 0.f};
  f32x4 acc10 = {0.f, 0.f, 0.f, 0.f}, acc11 = {0.f, 0.f, 0.f, 0.f};

  if (mm != 0) {                      // mm==0: skip ALL reads, epilogue writes zeros
    f32x4 wa[2][2], xa[2][2], wb[2][2], xb[2][2];   // two static pipeline stages
    LOADST(wa, xa, 0);
    int it = 0;
    for (; it + 2 < NIT; it += 2) {   // NIT even (128 or 44)
      LOADST(wb, xb, (it + 1) * 32);
      COMPST(wa, xa);
      LOADST(wa, xa, (it + 2) * 32);
      COMPST(wb, xb);
    }
    LOADST(wb, xb, (NIT - 1) * 32);
    COMPST(wa, xa);
    COMPST(wb, xb);
  }

  // Epilogue. C/D layout: col = lane&15, row = (lane>>4)*4 + i (m89-verified).
  // Lane stores cols n0+r and n0+16+r for rows m = mf*16 + q*4 + i; mask m>=mm.
  float* outg = out + (size_t)g * M_ * NOUT + colOff + n0;
#pragma unroll
  for (int i = 0; i < 4; ++i) {
    int m0 = q * 4 + i;          // rows 0..15  (acc0*)
    int m1 = 16 + m0;            // rows 16..31 (acc1*)
    outg[(size_t)m0 * NOUT + r]      = (m0 < mm) ? acc00[i] : 0.f;
    outg[(size_t)m0 * NOUT + 16 + r] = (m0 < mm) ? acc01[i] : 0.f;
    outg[(size_t)m1 * NOUT + r]      = (m1 < mm) ? acc10[i] : 0.f;
    outg[(size_t)m1 * NOUT + 16 + r] = (m1 < mm) ? acc11[i] : 0.f;
  }
}

extern "C" void kernel_launch(void* const* d_in, const int* in_sizes, int n_in,
                              void* d_out, int out_size, void* d_ws, size_t ws_size,
                              hipStream_t stream) {
  const float* x_ug     = (const float*)d_in[0];
  const float* w_ug     = (const float*)d_in[1];
  const float* x_dn     = (const float*)d_in[2];
  const float* w_dn     = (const float*)d_in[3];
  const int*   masked_m = (const int*)d_in[4];
  float*       out      = (float*)d_out;

  moe_masked_gemm<<<dim3(G_ * UPG), dim3(64), 0, stream>>>(
      x_ug, w_ug, x_dn, w_dn, masked_m, out);
}

// Round 5
// 122.896 us; speedup vs baseline: 1.1985x; 1.1985x over previous
//
#include <hip/hip_runtime.h>
#include <hip/hip_bf16.h>

// Grouped masked GEMM (DeepSeekMOE up/gate + down), fp32 in/out, bf16 MFMA.
// G=8, M=32. up/gate: K=4096,N=2816. down: K=1408,N=4096. out: [G,32,5632] f32.
//
// R4: wave-sized all-resident units (no barriers, no block tail) + W staged
// via global_load_lds at BK=128 -> 512B contiguous per W row per DMA instr
// (vs 128-256B in R0-R3; testing the DRAM-burst-efficiency theory).
// X read global->reg (L2/L3-served, XCD-affine g = blockIdx&7).

#define G_    8
#define M_    32
#define KUG   4096
#define NUG   2816
#define KDN   1408
#define NDN   4096
#define NOUT  (NUG + NDN)      // 5632
#define UPT   (NUG / 32)       // 88 up units per group
#define DNT   (NDN / 32)       // 128 down units per group
#define UPG   (UPT + DNT)      // 216 units per group
#define BK    128              // k-chunk per stage (512B per W row)

typedef __attribute__((ext_vector_type(8))) short bf16x8;
typedef __attribute__((ext_vector_type(4))) float f32x4;

typedef __attribute__((address_space(3))) float        lds_f32;
typedef const __attribute__((address_space(1))) float  gbl_f32;

// fp32 -> bf16 RNE via compiler (m240: don't hand-write cvt_pk asm).
__device__ __forceinline__ short f2bf(float x) {
  union { __hip_bfloat16 h; short s; } u;
  u.h = __hip_bfloat16(x);
  return u.s;
}

__device__ __forceinline__ bf16x8 cvt8(f32x4 lo, f32x4 hi) {
  bf16x8 o;
#pragma unroll
  for (int j = 0; j < 4; ++j) { o[j] = f2bf(lo[j]); o[4 + j] = f2bf(hi[j]); }
  return o;
}

__global__ __launch_bounds__(64, 2) void moe_masked_gemm(
    const float* __restrict__ x_ug, const float* __restrict__ w_ug,
    const float* __restrict__ x_dn, const float* __restrict__ w_dn,
    const int* __restrict__ masked_m, float* __restrict__ out) {
  // One wave per block; 16 KB W buffer => ~7 blocks/CU co-resident, LDS 112 KB.
  __shared__ float wbuf[32 * BK];

  int b = blockIdx.x;
  int g = b & 7;        // group -> XCD affinity (consecutive ids round-robin XCDs)
  int u = b >> 3;       // unit within group: [0,UPT) up, [UPT,UPG) down

  const float* wg;
  const float* xg;
  int K, NIT, n0, colOff;
  if (u < UPT) {
    K = KUG; NIT = KUG / BK; n0 = u * 32; colOff = 0;          // 32 iters
    wg = w_ug + ((size_t)g * NUG + n0) * KUG;
    xg = x_ug + (size_t)g * M_ * KUG;
  } else {
    int ud = u - UPT;
    K = KDN; NIT = KDN / BK; n0 = ud * 32; colOff = NUG;       // 11 iters
    wg = w_dn + ((size_t)g * NDN + n0) * KDN;
    xg = x_dn + (size_t)g * M_ * KDN;
  }

  int mm = masked_m[g];
  int t   = threadIdx.x;
  int r   = t & 15, q4 = t >> 4;     // frag coords: row-in-16, k-quad
  int l5  = t >> 5, q32 = t & 31;    // staging coords: row parity, 16B granule
  int s   = r & 7;                   // read-side swizzle key (== row&7 for this lane)

  f32x4 acc00 = {0.f, 0.f, 0.f, 0.f}, acc01 = {0.f, 0.f, 0.f, 0.f};
  f32x4 acc10 = {0.f, 0.f, 0.f, 0.f}, acc11 = {0.f, 0.f, 0.f, 0.f};

  if (mm != 0) {                     // mm==0: skip ALL reads, epilogue writes zeros
    for (int it = 0; it < NIT; ++it) {
      int k0 = it * BK;

      // --- Stage W tile [32 rows][BK] into LDS. DMA instr i covers rows
      // {2i, 2i+1}, 512B contiguous per row. LDS dest linear (gload_lds rule);
      // bank-swizzle via source granule permutation: LDS col c of row holds
      // global granule c ^ (row&7) (involution; read applies same XOR).
#pragma unroll
      for (int i = 0; i < 16; ++i) {
        int row = 2 * i + l5;
        int qs  = q32 ^ (row & 7);
        __builtin_amdgcn_global_load_lds(
            (gbl_f32*)(wg + (size_t)row * K + k0 + qs * 4),
            (lds_f32*)(wbuf + i * 256 + t * 4), 16, 0, 0);
      }

      // --- X fragments global->reg (L2/L3-resident, 688 KB/XCD working set).
      f32x4 xv[2][4][2];             // [m-frag][k-step][half] — fully unrolled
#pragma unroll
      for (int mf = 0; mf < 2; ++mf) {
#pragma unroll
        for (int ks = 0; ks < 4; ++ks) {
          const float* xp = xg + (size_t)(mf * 16 + r) * K + k0 + ks * 32 + q4 * 8;
          xv[mf][ks][0] = *(const f32x4*)xp;
          xv[mf][ks][1] = *(const f32x4*)(xp + 4);
        }
      }

      // gload_lds -> ds_read dependency is invisible to the compiler: drain
      // vmcnt explicitly, then fence the scheduler (rule #18).
      asm volatile("s_waitcnt vmcnt(0)" ::: "memory");
      __builtin_amdgcn_sched_barrier(0);

      // --- Compute: 4 k-steps x (2 m-frags x 2 n-frags) MFMA.
#pragma unroll
      for (int ks = 0; ks < 4; ++ks) {
        int g0 = (ks * 4 + q4) * 2;          // lane's logical 16B granule pair
        const float* row0 = wbuf + (size_t)r * BK;          // n-rows 0..15
        const float* row1 = wbuf + (size_t)(16 + r) * BK;   // n-rows 16..31
        f32x4 w0a = *(const f32x4*)(row0 + (((g0)     ^ s) << 2));
        f32x4 w0b = *(const f32x4*)(row0 + (((g0 + 1) ^ s) << 2));
        f32x4 w1a = *(const f32x4*)(row1 + (((g0)     ^ s) << 2));
        f32x4 w1b = *(const f32x4*)(row1 + (((g0 + 1) ^ s) << 2));
        bf16x8 b0 = cvt8(w0a, w0b);
        bf16x8 b1 = cvt8(w1a, w1b);
        bf16x8 a0 = cvt8(xv[0][ks][0], xv[0][ks][1]);
        bf16x8 a1 = cvt8(xv[1][ks][0], xv[1][ks][1]);
        acc00 = __builtin_amdgcn_mfma_f32_16x16x32_bf16(a0, b0, acc00, 0, 0, 0);
        acc01 = __builtin_amdgcn_mfma_f32_16x16x32_bf16(a0, b1, acc01, 0, 0, 0);
        acc10 = __builtin_amdgcn_mfma_f32_16x16x32_bf16(a1, b0, acc10, 0, 0, 0);
        acc11 = __builtin_amdgcn_mfma_f32_16x16x32_bf16(a1, b1, acc11, 0, 0, 0);
      }
      // Next iter's gload_lds can't hoist above this iter's ds_reads (both are
      // LDS memory ops on the same buffer -> compiler preserves order).
    }
  }

  // Epilogue. C/D layout: col = lane&15, row = (lane>>4)*4 + i (m89-verified).
  // Lane stores cols n0+r, n0+16+r for rows m = mf*16 + q4*4 + i; mask m >= mm.
  float* outg = out + (size_t)g * M_ * NOUT + colOff + n0;
#pragma unroll
  for (int i = 0; i < 4; ++i) {
    int m0 = q4 * 4 + i;         // rows 0..15  (acc0*)
    int m1 = 16 + m0;            // rows 16..31 (acc1*)
    outg[(size_t)m0 * NOUT + r]      = (m0 < mm) ? acc00[i] : 0.f;
    outg[(size_t)m0 * NOUT + 16 + r] = (m0 < mm) ? acc01[i] : 0.f;
    outg[(size_t)m1 * NOUT + r]      = (m1 < mm) ? acc10[i] : 0.f;
    outg[(size_t)m1 * NOUT + 16 + r] = (m1 < mm) ? acc11[i] : 0.f;
  }
}

extern "C" void kernel_launch(void* const* d_in, const int* in_sizes, int n_in,
                              void* d_out, int out_size, void* d_ws, size_t ws_size,
                              hipStream_t stream) {
  const float* x_ug     = (const float*)d_in[0];
  const float* w_ug     = (const float*)d_in[1];
  const float* x_dn     = (const float*)d_in[2];
  const float* w_dn     = (const float*)d_in[3];
  const int*   masked_m = (const int*)d_in[4];
  float*       out      = (float*)d_out;

  moe_masked_gemm<<<dim3(G_ * UPG), dim3(64), 0, stream>>>(
      x_ug, w_ug, x_dn, w_dn, masked_m, out);
}